// Round 4
// baseline (4777.341 us; speedup 1.0000x reference)
//
#include <hip/hip_runtime.h>

namespace {
constexpr int kB = 16, kT = 512, kIN = 16, kD = 128, kH = 256, kL = 136, kO = 32;
constexpr int kSteps = kT - 1;      // 511
constexpr int NBLK = 256;           // block k: d = k>>1, l-half = k&1
constexpr int NTHR = 512;
constexpr int LH   = 68;            // l per block
constexpr int NTILE = 5;            // 5 MFMA n-tiles (80 cols, 68 real)
// LDS layout (bytes)
constexpr int OFF_FW1 = 0;          // [64][144]  f32 pair-major (k/2, 2j+pair)  36864
constexpr int OFF_FW2 = 36864;      // [128][144] f32 pair-major                 73728
constexpr int OFF_AHI = 110592;     // [16][264] u16   8448
constexpr int OFF_ALO = 119040;     // [16][264] u16   8448
constexpr int OFF_DT  = 127488;     // [16][84]  f32   5376
constexpr int OFF_OMS = 132864;     // [16][68]  f32   4352
constexpr int OFF_Z1S = 137216;     // [256]     f32   1024
constexpr int OFF_HB  = 138240;     // [128]     f32    512
constexpr int OFF_HINC= 138752;     // [128]     f32    512
constexpr int OFF_RED = 139264;     // [16][8]   f32    512
constexpr size_t LDS_BYTES = 139776;
}

typedef __attribute__((ext_vector_type(8))) short short8;
typedef __attribute__((ext_vector_type(4))) float f32x4;

union PK { unsigned long long u; struct { float v; unsigned ep; } s; };

__device__ __forceinline__ float softplusf(float x) {
  return fmaxf(x, 0.0f) + log1pf(expf(-fabsf(x)));
}
__device__ __forceinline__ unsigned short f2bf(float x) {
  unsigned u = __float_as_uint(x);
  return (unsigned short)((u + 0x7FFFu + ((u >> 16) & 1u)) >> 16);
}
__device__ __forceinline__ float bf2f(unsigned short h) {
  return __uint_as_float(((unsigned)h) << 16);
}

__global__ void __launch_bounds__(256)
rde_init(const float* __restrict__ x0,
         const float* __restrict__ iw1, const float* __restrict__ ib1,
         const float* __restrict__ iw2, const float* __restrict__ ib2,
         const float* __restrict__ iw3, const float* __restrict__ ib3,
         float* __restrict__ hist) {
  __shared__ float xs[kIN];
  __shared__ __align__(16) float t1[kH];
  __shared__ __align__(16) float t2[kH];
  const int b = blockIdx.x, tid = threadIdx.x;
  if (tid < kIN) xs[tid] = x0[b*kIN + tid];
  __syncthreads();
  {
    float a = ib1[tid];
#pragma unroll
    for (int i = 0; i < kIN; ++i) a = fmaf(xs[i], iw1[tid*kIN + i], a);
    t1[tid] = softplusf(a);
  }
  __syncthreads();
  {
    const float4* wr = (const float4*)(iw2 + (size_t)tid*kH);
    float a = ib2[tid];
#pragma unroll 8
    for (int q = 0; q < kH/4; ++q) {
      float4 w = wr[q];
      a = fmaf(t1[4*q+0], w.x, a); a = fmaf(t1[4*q+1], w.y, a);
      a = fmaf(t1[4*q+2], w.z, a); a = fmaf(t1[4*q+3], w.w, a);
    }
    t2[tid] = softplusf(a);
  }
  __syncthreads();
  if (tid < kD) {
    const float4* wr = (const float4*)(iw3 + (size_t)tid*kH);
    float a = ib3[tid];
#pragma unroll 8
    for (int q = 0; q < kH/4; ++q) {
      float4 w = wr[q];
      a = fmaf(t2[4*q+0], w.x, a); a = fmaf(t2[4*q+1], w.y, a);
      a = fmaf(t2[4*q+2], w.z, a); a = fmaf(t2[4*q+3], w.w, a);
    }
    hist[(size_t)b*kD + tid] = a;
  }
}

__global__ void __launch_bounds__(NTHR, 2)
rde_scan(const float* __restrict__ lsg,
         const float* __restrict__ fw1, const float* __restrict__ fb1,
         const float* __restrict__ fw2, const float* __restrict__ fb2,
         const float* __restrict__ fw3, const float* __restrict__ fb3,
         float* __restrict__ hist,
         unsigned long long* z1x, unsigned* z2x, unsigned* z2snt,
         unsigned long long* partx) {
  extern __shared__ char smem[];
  float* fw1s = (float*)(smem + OFF_FW1);          // [64][144]
  float* fw2s = (float*)(smem + OFF_FW2);          // [128][144]
  unsigned short* Ahi = (unsigned short*)(smem + OFF_AHI);  // [16][264]
  unsigned short* Alo = (unsigned short*)(smem + OFF_ALO);
  float* Dt   = (float*)(smem + OFF_DT);           // [16][84]
  float* oms  = (float*)(smem + OFF_OMS);          // [16][68]
  float* z1s  = (float*)(smem + OFF_Z1S);          // [256]
  float* hb   = (float*)(smem + OFF_HB);           // [128]
  float* hinc = (float*)(smem + OFF_HINC);         // [128]
  float* red  = (float*)(smem + OFF_RED);          // [16][8]

  const int tid  = threadIdx.x;
  const int k    = blockIdx.x;
  const int wave = tid >> 6, lane = tid & 63;
  const int d_own = k >> 1, l0 = (k & 1) * LH;
  const bool isMLP = (k < 64);
  const int bmlp = k >> 2, qm = k & 3, j0 = qm * 64;
  const int jj = tid >> 3, ks = tid & 7;           // 8-way k-split

  // ---------------- prologue ----------------
  short8 bhi[8], blo[8];
  float biasv = 0.f;
  {
#pragma unroll
    for (int s = 0; s < 8; ++s) { bhi[s] = (short8)0; blo[s] = (short8)0; }
    if (wave < NTILE) {
      const int nl = wave*16 + (lane & 15);
      const int g  = lane >> 4;
      if (nl < LH) {
        const size_t row = (size_t)d_own*kL + l0 + nl;
        const float* wrow = fw3 + row*kH;
        biasv = fb3[row];
#pragma unroll
        for (int s = 0; s < 8; ++s) {
          const int k0 = s*32 + g*8;
          float4 v0 = *(const float4*)(wrow + k0);
          float4 v1 = *(const float4*)(wrow + k0 + 4);
          float vv[8] = {v0.x,v0.y,v0.z,v0.w,v1.x,v1.y,v1.z,v1.w};
#pragma unroll
          for (int e = 0; e < 8; ++e) {
            unsigned short hh = f2bf(vv[e]);
            bhi[s][e] = (short)hh;
            blo[s][e] = (short)f2bf(vv[e] - bf2f(hh));
          }
        }
      }
    }
  }
  float myfb1 = 0.f, myfb2 = 0.f;
  if (isMLP) {
    myfb1 = fb1[j0 + jj]; myfb2 = fb2[j0 + jj];
    // pair-major transposes: w[(k>>1)*144 + 2j + (k&1)]
    for (int i = tid; i < 64*32; i += NTHR) {
      int j = i >> 5, q = i & 31;
      float4 v = *(const float4*)(fw1 + (size_t)(j0 + j)*kD + q*4);
      *(float2*)(fw1s + (2*q  )*144 + 2*j) = make_float2(v.x, v.y);
      *(float2*)(fw1s + (2*q+1)*144 + 2*j) = make_float2(v.z, v.w);
    }
    for (int i = tid; i < 64*64; i += NTHR) {
      int j = i >> 6, q = i & 63;
      float4 v = *(const float4*)(fw2 + (size_t)(j0 + j)*kH + q*4);
      *(float2*)(fw2s + (2*q  )*144 + 2*j) = make_float2(v.x, v.y);
      *(float2*)(fw2s + (2*q+1)*144 + 2*j) = make_float2(v.z, v.w);
    }
    for (int i = tid; i < kD; i += NTHR) hb[i] = hist[(size_t)bmlp*kD + i];
  }
  __syncthreads();

  // ---------------- scan ----------------
  for (int t = 0; t < kSteps; ++t) {
    const unsigned epw = (unsigned)(t + 1);

    if (!isMLP) {
      // lsg prefetch (tid>=256); MLP blocks do it later, overlapped with z1 poll
      if (tid >= 256) {
        int c = tid - 256;
#pragma unroll 2
        for (int rep = 0; rep < 2; ++rep) {
          int cc = c + rep*256;
          if (cc < 272) {
            int bb = cc / 17, ii = cc % 17;
            float4 v = *(const float4*)(lsg + ((size_t)bb*kSteps + t)*kL + l0 + ii*4);
            *(float4*)(oms + bb*LH + ii*4) = v;
          }
        }
      }
    } else {
      // ---- z1: all 8 waves, 8-way k-split, j = tid>>3 ----
      {
        float a = 0.f;
#pragma unroll
        for (int kh = ks; kh < 64; kh += 8) {
          float2 w  = *(const float2*)(fw1s + kh*144 + 2*jj);
          float2 h2 = *(const float2*)(hb + 2*kh);
          a = fmaf(h2.x, w.x, a); a = fmaf(h2.y, w.y, a);
        }
        a += __shfl_xor(a, 1); a += __shfl_xor(a, 2); a += __shfl_xor(a, 4);
        if (ks == 0) {
          PK p; p.s.v = softplusf(a + myfb1); p.s.ep = epw;
          __hip_atomic_store(z1x + bmlp*kH + j0 + jj, p.u,
                             __ATOMIC_RELAXED, __HIP_MEMORY_SCOPE_AGENT);
        }
      }
      // lsg prefetch overlapped with z1 gather-poll
      if (tid >= 256) {
        int c = tid - 256;
#pragma unroll 2
        for (int rep = 0; rep < 2; ++rep) {
          int cc = c + rep*256;
          if (cc < 272) {
            int bb = cc / 17, ii = cc % 17;
            float4 v = *(const float4*)(lsg + ((size_t)bb*kSteps + t)*kL + l0 + ii*4);
            *(float4*)(oms + bb*LH + ii*4) = v;
          }
        }
      }
      // ---- gather full z1[b] (epoch-embedded poll) ----
      if (tid < 128) {
#pragma unroll
        for (int s = 0; s < 2; ++s) {
          int idx = tid*2 + s;
          PK q;
          for (;;) {
            q.u = __hip_atomic_load(z1x + bmlp*kH + idx,
                                    __ATOMIC_RELAXED, __HIP_MEMORY_SCOPE_AGENT);
            if (q.s.ep == epw) break;
            __builtin_amdgcn_s_sleep(1);
          }
          z1s[idx] = q.s.v;
        }
      }
      __syncthreads();
      asm volatile("" ::: "memory");
      // ---- z2: all 8 waves ----
      {
        float a = 0.f;
#pragma unroll
        for (int kh = ks; kh < 128; kh += 8) {
          float2 w  = *(const float2*)(fw2s + kh*144 + 2*jj);
          float2 z2v = *(const float2*)(z1s + 2*kh);
          a = fmaf(z2v.x, w.x, a); a = fmaf(z2v.y, w.y, a);
        }
        a += __shfl_xor(a, 1); a += __shfl_xor(a, 2); a += __shfl_xor(a, 4);
        if (ks == 0) {
          float v = softplusf(a + myfb2);
          unsigned short hh = f2bf(v);
          unsigned short ll = f2bf(v - bf2f(hh));
          __hip_atomic_store(z2x + bmlp*kH + j0 + jj,
                             (unsigned)hh | ((unsigned)ll << 16),
                             __ATOMIC_RELAXED, __HIP_MEMORY_SCOPE_AGENT);
        }
      }
      __syncthreads();                               // drain all z2 stores
      if (tid == 0)
        __hip_atomic_store(z2snt + (bmlp*4 + qm)*32, epw,
                           __ATOMIC_RELAXED, __HIP_MEMORY_SCOPE_AGENT);
    }

    // ---- all blocks: wait z2 sentinels, read packed hi/lo into A planes ----
    if (tid < 64) {
      for (;;) {
        unsigned e = __hip_atomic_load(z2snt + tid*32,
                                       __ATOMIC_RELAXED, __HIP_MEMORY_SCOPE_AGENT);
        if (e == epw) break;
        __builtin_amdgcn_s_sleep(2);
      }
    }
    __syncthreads();
    asm volatile("" ::: "memory");
    {
      unsigned pk[8];
      const unsigned* src = z2x + tid*8;
#pragma unroll
      for (int i = 0; i < 8; ++i)
        pk[i] = __hip_atomic_load(src + i, __ATOMIC_RELAXED, __HIP_MEMORY_SCOPE_AGENT);
      const int e0 = tid*8, m = e0 >> 8, kk = e0 & 255;
      unsigned short* ph = Ahi + m*264 + kk;
      unsigned short* pl = Alo + m*264 + kk;
#pragma unroll
      for (int i = 0; i < 4; ++i) {
        unsigned a = pk[2*i], b = pk[2*i+1];
        *(unsigned*)(ph + 2*i) = (a & 0xffffu) | (b << 16);
        *(unsigned*)(pl + 2*i) = (a >> 16) | (b & 0xffff0000u);
      }
    }
    __syncthreads();

    // ---- MFMA: waves 0-4, tile = wave (16 cols), K=256, hi/lo 3-product ----
    if (wave < NTILE) {
      f32x4 acc = {biasv, biasv, biasv, biasv};
      const unsigned short* arh = Ahi + (lane & 15)*264;
      const unsigned short* arl = Alo + (lane & 15)*264;
      const int g = lane >> 4;
#pragma unroll
      for (int s = 0; s < 8; ++s) {
        short8 ah = *(const short8*)(arh + s*32 + g*8);
        short8 al = *(const short8*)(arl + s*32 + g*8);
        acc = __builtin_amdgcn_mfma_f32_16x16x32_bf16(ah, bhi[s], acc, 0, 0, 0);
        acc = __builtin_amdgcn_mfma_f32_16x16x32_bf16(ah, blo[s], acc, 0, 0, 0);
        acc = __builtin_amdgcn_mfma_f32_16x16x32_bf16(al, bhi[s], acc, 0, 0, 0);
      }
#pragma unroll
      for (int r = 0; r < 4; ++r)
        Dt[(g*4 + r)*84 + wave*16 + (lane & 15)] = acc[r];
    }
    __syncthreads();

    // ---- contraction: tanh * logsig, reduce over l ----
    {
      const int b3 = tid & 15, lb = tid >> 4;   // lb 0..31
      float p = tanhf(Dt[b3*84 + lb     ]) * oms[b3*LH + lb     ]
              + tanhf(Dt[b3*84 + lb + 32]) * oms[b3*LH + lb + 32];
      if (lb < 4)
        p += tanhf(Dt[b3*84 + lb + 64]) * oms[b3*LH + lb + 64];
      p += __shfl_xor(p, 16); p += __shfl_xor(p, 32);
      if (lane < 16) red[lane*8 + wave] = p;
    }
    __syncthreads();
    if (tid < 16) {
      float s = 0.f;
#pragma unroll
      for (int j = 0; j < 8; ++j) s += red[tid*8 + j];
      PK p; p.s.v = s; p.s.ep = epw;
      __hip_atomic_store(partx + tid*NBLK + k, p.u,
                         __ATOMIC_RELAXED, __HIP_MEMORY_SCOPE_AGENT);
    }

    // ---- MLP blocks: gather partials (epoch-embedded), update h ----
    if (isMLP) {
      float pval = 0.f;
      if (tid < 256) {
        PK q;
        for (;;) {
          q.u = __hip_atomic_load(partx + bmlp*NBLK + tid,
                                  __ATOMIC_RELAXED, __HIP_MEMORY_SCOPE_AGENT);
          if (q.s.ep == epw) break;
          __builtin_amdgcn_s_sleep(2);
        }
        pval = q.s.v;
        float p2 = pval + __shfl_xor(pval, 1);
        if ((tid & 1) == 0) hinc[tid >> 1] = p2;
      }
      __syncthreads();
      if (tid < 128) {
        float hn = hb[tid] + hinc[tid];
        hb[tid] = hn;
        if (qm == 0) hist[((size_t)(t+1)*kB + bmlp)*kD + tid] = hn;
      }
      __syncthreads();
    }
  }
}

__global__ void __launch_bounds__(512)
rde_readout(const float* __restrict__ hist, const float* __restrict__ rw,
            const float* __restrict__ rb, float* __restrict__ out) {
  const int t = blockIdx.x, tid = threadIdx.x;
  const int b = tid >> 5, o = tid & 31;
  const float4* hr = (const float4*)(hist + ((size_t)t*kB + b)*kD);
  const float4* wr = (const float4*)(rw + (size_t)o*kD);
  float a = rb[o];
#pragma unroll 8
  for (int q = 0; q < kD/4; ++q) {
    float4 h4 = hr[q], w4 = wr[q];
    a = fmaf(h4.x,w4.x,a); a = fmaf(h4.y,w4.y,a);
    a = fmaf(h4.z,w4.z,a); a = fmaf(h4.w,w4.w,a);
  }
  out[((size_t)b*kT + t)*kO + o] = a;
}

extern "C" void kernel_launch(void* const* d_in, const int* in_sizes, int n_in,
                              void* d_out, int out_size, void* d_ws, size_t ws_size,
                              hipStream_t stream) {
  const float* x0  = (const float*)d_in[0];
  const float* lsg = (const float*)d_in[1];
  const float* iw1 = (const float*)d_in[2];
  const float* ib1 = (const float*)d_in[3];
  const float* iw2 = (const float*)d_in[4];
  const float* ib2 = (const float*)d_in[5];
  const float* iw3 = (const float*)d_in[6];
  const float* ib3 = (const float*)d_in[7];
  const float* fw1 = (const float*)d_in[8];
  const float* fb1 = (const float*)d_in[9];
  const float* fw2 = (const float*)d_in[10];
  const float* fb2 = (const float*)d_in[11];
  const float* fw3 = (const float*)d_in[12];
  const float* fb3 = (const float*)d_in[13];
  const float* rw  = (const float*)d_in[14];
  const float* rb  = (const float*)d_in[15];
  float* out = (float*)d_out;

  float* hist = (float*)d_ws;                                  // 512*16*128 f32
  unsigned long long* z1x = (unsigned long long*)(hist + (size_t)kT*kB*kD); // 4096 u64
  unsigned* z2x   = (unsigned*)(z1x + kB*kH);                  // 4096 u32
  unsigned* z2snt = z2x + kB*kH;                               // 64*32 u32
  unsigned long long* partx = (unsigned long long*)(z2snt + 64*32); // 16*256 u64

  // zero all exchange buffers (epochs) — deterministic start each launch
  size_t xbytes = (size_t)kB*kH*8 + (size_t)kB*kH*4 + 64*32*4 + (size_t)kB*NBLK*8;
  hipMemsetAsync(z1x, 0, xbytes, stream);
  hipFuncSetAttribute((const void*)rde_scan,
                      hipFuncAttributeMaxDynamicSharedMemorySize, (int)LDS_BYTES);

  rde_init<<<kB, 256, 0, stream>>>(x0, iw1, ib1, iw2, ib2, iw3, ib3, hist);

  void* args[] = { (void*)&lsg, (void*)&fw1, (void*)&fb1, (void*)&fw2, (void*)&fb2,
                   (void*)&fw3, (void*)&fb3, (void*)&hist, (void*)&z1x, (void*)&z2x,
                   (void*)&z2snt, (void*)&partx };
  hipLaunchCooperativeKernel((const void*)rde_scan, dim3(NBLK), dim3(NTHR),
                             args, (unsigned)LDS_BYTES, stream);

  rde_readout<<<kT, 512, 0, stream>>>(hist, rw, rb, out);
}